// Round 13
// baseline (296.140 us; speedup 1.0000x reference)
//
#include <hip/hip_runtime.h>

#define B_ROWS 8192
#define WIDTH  512
#define DEPTH  7
#define CIN    4096
#define EPS    1e-5f
#define SLOPE  0.01f

typedef __attribute__((ext_vector_type(8))) short short8;
typedef __attribute__((ext_vector_type(4))) short short4v;
typedef __attribute__((ext_vector_type(4))) float f32x4;
typedef __attribute__((ext_vector_type(16))) float f32x16;

// round-to-nearest-even f32 -> bf16 bits
__device__ inline short f2bf(float f) {
  unsigned u = __builtin_bit_cast(unsigned, f);
  unsigned r = (u + 0x7FFFu + ((u >> 16) & 1u)) >> 16;
  return (short)r;
}

__device__ inline float bf2f(short b) {
  unsigned u = ((unsigned)(unsigned short)b) << 16;
  return __builtin_bit_cast(float, u);
}

__device__ inline void gl_lds16(const void* g, void* l) {
  __builtin_amdgcn_global_load_lds(
      (const __attribute__((address_space(1))) unsigned*)g,
      (__attribute__((address_space(3))) unsigned*)l, 16, 0, 0);
}

// ------- merged prologue: convw (k8-blocked) + initx + zero sums --------------
// W' layout per layer: [k/8][512 cols][8] so GEMM loads b-fragments coalesced
// straight from global (no LDS staging for B). Verified in R9 (passed).
struct WP { const float* p[7]; };

template <int L>
__device__ inline void convw_one(const float* __restrict__ src,
                                 short* __restrict__ dst, int idx) {
  constexpr int FAN = 512 * (L + 1);
  int col = idx / FAN;            // compile-time magic-mul division
  int k = idx - col * FAN;        // multiple of 8 (idx is 8-aligned)
  f32x4 v0 = *(const f32x4*)(src + idx);
  f32x4 v1 = *(const f32x4*)(src + idx + 4);
  short8 o;
  o[0] = f2bf(v0.x); o[1] = f2bf(v0.y); o[2] = f2bf(v0.z); o[3] = f2bf(v0.w);
  o[4] = f2bf(v1.x); o[5] = f2bf(v1.y); o[6] = f2bf(v1.z); o[7] = f2bf(v1.w);
  *(short8*)(dst + ((long)(k >> 3) << 12) + (col << 3)) = o;
}

__global__ __launch_bounds__(256) void prolog(WP wp, short* __restrict__ wbf,
                                              const float* __restrict__ x,
                                              const float* __restrict__ wc,
                                              short* __restrict__ lastbf,
                                              float* __restrict__ logit,
                                              float* __restrict__ sumsz) {
  if (blockIdx.x >= 2048) {
    int e = (int)(((long)(blockIdx.x - 2048) * 256 + threadIdx.x) * 8);
    if      (e < 262144)  convw_one<0>(wp.p[0], wbf,           e);
    else if (e < 786432)  convw_one<1>(wp.p[1], wbf + 262144,  e - 262144);
    else if (e < 1572864) convw_one<2>(wp.p[2], wbf + 786432,  e - 786432);
    else if (e < 2621440) convw_one<3>(wp.p[3], wbf + 1572864, e - 1572864);
    else if (e < 3932160) convw_one<4>(wp.p[4], wbf + 2621440, e - 2621440);
    else if (e < 5505024) convw_one<5>(wp.p[5], wbf + 3932160, e - 3932160);
    else                  convw_one<6>(wp.p[6], wbf + 5505024, e - 5505024);
    return;
  }
  int gid = blockIdx.x * 256 + threadIdx.x;
  if (gid < DEPTH * 1024) sumsz[gid] = 0.f;  // zero all layers' stats buffers
  int w = threadIdx.x >> 6, l = threadIdx.x & 63;
  int r = blockIdx.x * 4 + w;
  const float* xr = x + (long)r * 512 + l * 8;
  f32x4 v0 = *(const f32x4*)xr;
  f32x4 v1 = *(const f32x4*)(xr + 4);
  const float* wcr = wc + l * 8;
  float acc = 0.f;
  short8 ob;
#pragma unroll
  for (int j = 0; j < 4; ++j) { acc += v0[j] * wcr[j];     ob[j]     = f2bf(v0[j]); }
#pragma unroll
  for (int j = 0; j < 4; ++j) { acc += v1[j] * wcr[4 + j]; ob[4 + j] = f2bf(v1[j]); }
  *(short8*)&lastbf[(long)r * CIN + l * 8] = ob;
#pragma unroll
  for (int off = 32; off; off >>= 1) acc += __shfl_xor(acc, off);
  if (l == 0) logit[r] = acc;
}

// ---------------- bf16 MFMA GEMM + fused column stats -------------------------
// R12's proven structure with ONE isolated change: B never touches LDS.
// BM=128, BN=64, BK=64, grid (64,8) = 512 blocks -> 2 blocks/CU, 4 waves,
// wave ks owns the k16 slice of each BK=64 tile, full 128x64 tile, 32x32x16
// MFMA, acc[4][2] f32x16. A: dbuf LDS 2x16KB, XOR-swizzle byte^((row&7)<<4)
// via pre-swizzled source; unique-read (each staged byte read exactly once).
// B: k8-blocked global layout, per-wave coalesced short8 loads, 1 tile ahead,
// compiler-scheduled waits (no asm). Cuts per-iter LDS traffic 48KB -> 32KB.
// Epilogue: 4-pass combine in Red (aliases staging), bf16 C + f32 stats.
__global__ __launch_bounds__(256, 2) void gemm_fused(const short* __restrict__ A,
                                                     const short* __restrict__ Bw,
                                                     short* __restrict__ C,
                                                     float* __restrict__ sums,
                                                     int K) {
  __shared__ __align__(16) char smem[32768];  // 2 x 16KB A buffers (= Red size)
  int t = threadIdx.x;
  int ks = t >> 6, l = t & 63;
  int l31 = l & 31, hi = l >> 5;
  int bm = blockIdx.x, bn = blockIdx.y;
  const short* Ab = A + (long)(bm * 128) * CIN;

  f32x16 acc[4][2];
#pragma unroll
  for (int m = 0; m < 4; ++m)
#pragma unroll
    for (int n = 0; n < 2; ++n)
#pragma unroll
      for (int r = 0; r < 16; ++r) acc[m][n][r] = 0.f;

  // A staging: 16 x 1KB chunks/tile; wave ks stages chunks 4ks..4ks+3.
  // dest row = chunk*8 + (l>>3); source col pre-swizzled so read-side
  // byte^((row&7)<<4) is the matching involution.
  int l8 = l >> 3;
  int scol = ((l & 7) ^ l8) << 3;

#define STAGE(buf, k0)                                                                     \
  {                                                                                        \
    char* base = smem + (buf) * 16384;                                                     \
    int c0 = ks * 4;                                                                       \
    gl_lds16(Ab + (long)((c0    ) * 8 + l8) * CIN + (k0) + scol, base + (c0    ) * 1024);  \
    gl_lds16(Ab + (long)((c0 + 1) * 8 + l8) * CIN + (k0) + scol, base + (c0 + 1) * 1024);  \
    gl_lds16(Ab + (long)((c0 + 2) * 8 + l8) * CIN + (k0) + scol, base + (c0 + 2) * 1024);  \
    gl_lds16(Ab + (long)((c0 + 3) * 8 + l8) * CIN + (k0) + scol, base + (c0 + 3) * 1024);  \
  }

  // B: per-lane base into k8-blocked layout (verified R9). Tile tt, frag n:
  // 16B at ((tt*8 + ks*2 + hi) * 4096 + (bn*64 + n*32 + l31) * 8) elements.
  const short* Bp = Bw + ((ks * 2 + hi) << 12) + ((bn * 64 + l31) << 3);
#define BLOAD(d0, d1, tt)                          \
  {                                                \
    const short* bp_ = Bp + ((long)(tt) << 15);    \
    d0 = *(const short8*)bp_;                      \
    d1 = *(const short8*)(bp_ + 256);              \
  }

  short8 bc0, bc1, bn0, bn1;
  BLOAD(bc0, bc1, 0);
  STAGE(0, 0);
  __syncthreads();

  // fragment k-slice within a 128B LDS row: kb = ks*32 + hi*16 bytes.
  int kb = ks * 32 + hi * 16;
  int sw = (l & 7) << 4;  // row&7 == l&7 since frag rows are m*32 + l31

  int nt = K >> 6;
  int cur = 0;
  for (int tix = 0; tix < nt; ++tix) {
    if (tix + 1 < nt) {
      STAGE(cur ^ 1, (tix + 1) << 6);
      BLOAD(bn0, bn1, tix + 1);
    }
    const char* AsC = smem + cur * 16384;
    short8 a[4];
#pragma unroll
    for (int m = 0; m < 4; ++m)
      a[m] = *(const short8*)(AsC + (m * 32 + l31) * 128 + (kb ^ sw));
#pragma unroll
    for (int m = 0; m < 4; ++m) {
      acc[m][0] = __builtin_amdgcn_mfma_f32_32x32x16_bf16(a[m], bc0, acc[m][0], 0, 0, 0);
      acc[m][1] = __builtin_amdgcn_mfma_f32_32x32x16_bf16(a[m], bc1, acc[m][1], 0, 0, 0);
    }
    __syncthreads();  // staged buf^1 complete + all reads of cur done
    cur ^= 1;
    bc0 = bn0; bc1 = bn1;
  }

  // ---- combine 4 K-quarters (Red aliases staging LDS), write bf16 C, stats ----
  float* Red = (float*)smem;  // 128x64 f32 = 32KB
#define RIDX(m, n, r) (((m) * 32 + ((r) & 3) + 8 * ((r) >> 2) + 4 * hi) * 64 + (n) * 32 + l31)
  if (ks == 3) {
#pragma unroll
    for (int m = 0; m < 4; ++m)
#pragma unroll
      for (int n = 0; n < 2; ++n)
#pragma unroll
        for (int r = 0; r < 16; ++r) Red[RIDX(m, n, r)] = acc[m][n][r];
  }
  __syncthreads();
  if (ks == 2) {
#pragma unroll
    for (int m = 0; m < 4; ++m)
#pragma unroll
      for (int n = 0; n < 2; ++n)
#pragma unroll
        for (int r = 0; r < 16; ++r) Red[RIDX(m, n, r)] += acc[m][n][r];
  }
  __syncthreads();
  if (ks == 1) {
#pragma unroll
    for (int m = 0; m < 4; ++m)
#pragma unroll
      for (int n = 0; n < 2; ++n)
#pragma unroll
        for (int r = 0; r < 16; ++r) Red[RIDX(m, n, r)] += acc[m][n][r];
  }
  __syncthreads();
  if (ks == 0) {
    short* Cb = C + (long)(bm * 128) * WIDTH + bn * 64;
#pragma unroll
    for (int n = 0; n < 2; ++n) {
      float s = 0.f, q = 0.f;
#pragma unroll
      for (int m = 0; m < 4; ++m) {
#pragma unroll
        for (int r = 0; r < 16; ++r) {
          int cr = (r & 3) + 8 * (r >> 2) + 4 * hi;
          float v = acc[m][n][r] + Red[RIDX(m, n, r)];
          Cb[(long)(m * 32 + cr) * WIDTH + n * 32 + l31] = f2bf(v);
          s += v; q += v * v;
        }
      }
      s += __shfl_xor(s, 32);
      q += __shfl_xor(q, 32);
      if (l < 32) {
        int colg = bn * 64 + n * 32 + l;
        atomicAdd(&sums[colg], s);
        atomicAdd(&sums[WIDTH + colg], q);
      }
    }
  }
#undef RIDX
#undef BLOAD
#undef STAGE
}

// ---------------- BN + LeakyReLU + noise + classifier partial + bf16 store ----
__global__ __launch_bounds__(256) void bnact(const short* __restrict__ h,
                                             const float* __restrict__ sums,
                                             const float* __restrict__ gamma,
                                             const float* __restrict__ beta,
                                             const float* __restrict__ noise,
                                             const float* __restrict__ wc,
                                             short* __restrict__ lastseg,
                                             float* __restrict__ logit) {
  int w = threadIdx.x >> 6, l = threadIdx.x & 63;
  int r = blockIdx.x * 4 + w;
  int c = l * 8;
  const float invB = 1.0f / 8192.0f;
  short8 hb = *(const short8*)&h[(long)r * WIDTH + c];
  f32x4 n0 = *(const f32x4*)&noise[(long)r * WIDTH + c];
  f32x4 n1 = *(const f32x4*)&noise[(long)r * WIDTH + c + 4];
  float acc = 0.f;
  short8 ob;
#pragma unroll
  for (int j = 0; j < 8; ++j) {
    int cc = c + j;
    float hv = bf2f(hb[j]);
    float nv = j < 4 ? n0[j] : n1[j - 4];
    float mean = sums[cc] * invB;
    float var = sums[WIDTH + cc] * invB - mean * mean;
    float v = (hv - mean) * rsqrtf(var + EPS);
    v = v * gamma[cc] + beta[cc];
    v = v >= 0.f ? v : SLOPE * v;
    v *= nv;
    acc += v * wc[cc];
    ob[j] = f2bf(v);
  }
  *(short8*)&lastseg[(long)r * CIN + c] = ob;
#pragma unroll
  for (int off = 32; off; off >>= 1) acc += __shfl_xor(acc, off);
  if (l == 0) logit[r] += acc;  // one wave per row: no race
}

// ---- last layer: BN + act + classifier partial + sigmoid straight to out ----
__global__ __launch_bounds__(256) void bnact_last(const short* __restrict__ h,
                                                  const float* __restrict__ sums,
                                                  const float* __restrict__ gamma,
                                                  const float* __restrict__ beta,
                                                  const float* __restrict__ noise,
                                                  const float* __restrict__ wc,
                                                  const float* __restrict__ logit,
                                                  const float* __restrict__ bc,
                                                  float* __restrict__ out) {
  int w = threadIdx.x >> 6, l = threadIdx.x & 63;
  int r = blockIdx.x * 4 + w;
  int c = l * 8;
  const float invB = 1.0f / 8192.0f;
  short8 hb = *(const short8*)&h[(long)r * WIDTH + c];
  f32x4 n0 = *(const f32x4*)&noise[(long)r * WIDTH + c];
  f32x4 n1 = *(const f32x4*)&noise[(long)r * WIDTH + c + 4];
  float acc = 0.f;
#pragma unroll
  for (int j = 0; j < 8; ++j) {
    int cc = c + j;
    float hv = bf2f(hb[j]);
    float nv = j < 4 ? n0[j] : n1[j - 4];
    float mean = sums[cc] * invB;
    float var = sums[WIDTH + cc] * invB - mean * mean;
    float v = (hv - mean) * rsqrtf(var + EPS);
    v = v * gamma[cc] + beta[cc];
    v = v >= 0.f ? v : SLOPE * v;
    v *= nv;
    acc += v * wc[cc];
  }
#pragma unroll
  for (int off = 32; off; off >>= 1) acc += __shfl_xor(acc, off);
  if (l == 0) {
    float z = logit[r] + acc + bc[0];
    out[r] = 1.0f / (1.0f + expf(-z));
  }
}

extern "C" void kernel_launch(void* const* d_in, const int* in_sizes, int n_in,
                              void* d_out, int out_size, void* d_ws, size_t ws_size,
                              hipStream_t stream) {
  (void)in_sizes; (void)n_in; (void)out_size; (void)ws_size;
  const float* x     = (const float*)d_in[0];
  WP wp;
  for (int i = 0; i < 7; ++i) wp.p[i] = (const float*)d_in[1 + i];
  // d_in[8] = b (linear bias) — cancels exactly through training-mode BN; unused.
  const float* gamma = (const float*)d_in[9];
  const float* beta  = (const float*)d_in[10];
  const float* Wc    = (const float*)d_in[11];
  const float* bc    = (const float*)d_in[12];
  const float* noise = (const float*)d_in[13];

  char* ws = (char*)d_ws;
  short* lastbf = (short*)ws;                               // 8192*4096 bf16 = 64 MiB
  short* hpre   = (short*)(ws + 67108864);                  // 8192*512 bf16 = 8 MiB
  short* wbf    = (short*)(ws + 67108864 + 16777216);       // 7.34M bf16    = 14 MiB
  float* sums   = (float*)(ws + 67108864 + 16777216 + 14680064);   // 7*1024 f32
  float* logit  = (float*)(ws + 67108864 + 16777216 + 14680064 + 28672);  // 8192 f32

  prolog<<<5632, 256, 0, stream>>>(wp, wbf, x, Wc, lastbf, logit, sums);

  long woff = 0;
  for (int i = 0; i < DEPTH; ++i) {
    int K = 512 * (i + 1);
    gemm_fused<<<dim3(64, 8), 256, 0, stream>>>(lastbf, wbf + woff, hpre,
                                                sums + i * 1024, K);
    if (i < DEPTH - 1) {
      bnact<<<2048, 256, 0, stream>>>(hpre, sums + i * 1024,
                                      gamma + i * 512, beta + i * 512,
                                      noise + (long)i * B_ROWS * WIDTH,
                                      Wc + 512 + i * 512,
                                      lastbf + 512 + (long)i * 512, logit);
    } else {
      bnact_last<<<2048, 256, 0, stream>>>(hpre, sums + i * 1024,
                                           gamma + i * 512, beta + i * 512,
                                           noise + (long)i * B_ROWS * WIDTH,
                                           Wc + 512 + i * 512,
                                           logit, bc, (float*)d_out);
    }
    woff += (long)512 * K;
  }
}

// Round 14
// 270.176 us; speedup vs baseline: 1.0961x; 1.0961x over previous
//
#include <hip/hip_runtime.h>

#define B_ROWS 8192
#define WIDTH  512
#define DEPTH  7
#define CIN    4096
#define EPS    1e-5f
#define SLOPE  0.01f

typedef __attribute__((ext_vector_type(8))) short short8;
typedef __attribute__((ext_vector_type(4))) short short4v;
typedef __attribute__((ext_vector_type(4))) float f32x4;
typedef __attribute__((ext_vector_type(16))) float f32x16;

// round-to-nearest-even f32 -> bf16 bits
__device__ inline short f2bf(float f) {
  unsigned u = __builtin_bit_cast(unsigned, f);
  unsigned r = (u + 0x7FFFu + ((u >> 16) & 1u)) >> 16;
  return (short)r;
}

__device__ inline float bf2f(short b) {
  unsigned u = ((unsigned)(unsigned short)b) << 16;
  return __builtin_bit_cast(float, u);
}

__device__ inline void gl_lds16(const void* g, void* l) {
  __builtin_amdgcn_global_load_lds(
      (const __attribute__((address_space(1))) unsigned*)g,
      (__attribute__((address_space(3))) unsigned*)l, 16, 0, 0);
}

// ------- merged prologue: convw (8 elems/thread) + initx + zero sums ----------
// blocks [0,2048): x -> bf16 concat buffer + classifier partial + zero sums
// blocks [2048,5632): 7 fp32 W's -> packed bf16 (8 elems/thread)
struct WP { const float* p[7]; };

__global__ __launch_bounds__(256) void prolog(WP wp, short* __restrict__ wbf,
                                              const float* __restrict__ x,
                                              const float* __restrict__ wc,
                                              short* __restrict__ lastbf,
                                              float* __restrict__ logit,
                                              float* __restrict__ sumsz) {
  if (blockIdx.x >= 2048) {
    long e = ((long)(blockIdx.x - 2048) * 256 + threadIdx.x) * 8;
    int layer; long base;
    if      (e < 262144L)  { layer = 0; base = 0; }
    else if (e < 786432L)  { layer = 1; base = 262144L; }
    else if (e < 1572864L) { layer = 2; base = 786432L; }
    else if (e < 2621440L) { layer = 3; base = 1572864L; }
    else if (e < 3932160L) { layer = 4; base = 2621440L; }
    else if (e < 5505024L) { layer = 5; base = 3932160L; }
    else                   { layer = 6; base = 5505024L; }
    const float* src = wp.p[layer] + (e - base);
    f32x4 v0 = *(const f32x4*)src;
    f32x4 v1 = *(const f32x4*)(src + 4);
    short8 o;
    o[0] = f2bf(v0.x); o[1] = f2bf(v0.y); o[2] = f2bf(v0.z); o[3] = f2bf(v0.w);
    o[4] = f2bf(v1.x); o[5] = f2bf(v1.y); o[6] = f2bf(v1.z); o[7] = f2bf(v1.w);
    *(short8*)(wbf + e) = o;
    return;
  }
  int gid = blockIdx.x * 256 + threadIdx.x;
  if (gid < DEPTH * 1024) sumsz[gid] = 0.f;  // zero all layers' stats buffers
  int w = threadIdx.x >> 6, l = threadIdx.x & 63;
  int r = blockIdx.x * 4 + w;
  const float* xr = x + (long)r * 512 + l * 8;
  f32x4 v0 = *(const f32x4*)xr;
  f32x4 v1 = *(const f32x4*)(xr + 4);
  const float* wcr = wc + l * 8;
  float acc = 0.f;
  short8 ob;
#pragma unroll
  for (int j = 0; j < 4; ++j) { acc += v0[j] * wcr[j];     ob[j]     = f2bf(v0[j]); }
#pragma unroll
  for (int j = 0; j < 4; ++j) { acc += v1[j] * wcr[4 + j]; ob[4 + j] = f2bf(v1[j]); }
  *(short8*)&lastbf[(long)r * CIN + l * 8] = ob;
#pragma unroll
  for (int off = 32; off; off >>= 1) acc += __shfl_xor(acc, off);
  if (l == 0) logit[r] = acc;
}

// ---------------- bf16 MFMA GEMM + fused column stats -------------------------
// BM=128, BN=64, BK=64, grid (64,8) = 512 blocks -> 2 blocks/CU.
// __launch_bounds__(256,2): 256-VGPR budget, NO spill (R7's (256,3) forced an
// 84-VGPR allocation and spilled the 128-VGPR accumulator to scratch — never
// cap below the accumulator footprint; HW VGPR steps are 64/128/256).
// 4 waves; wave ks owns the k16 slice ks of each BK=64 tile and covers the
// FULL 128x64 output tile with 32x32x16 MFMA (acc[4][2] f32x16).
// LDS: dbuf x (As 16KB + Bs 8KB), XOR-swizzled (byte ^ ((row&7)<<4)) via
// pre-swizzled global source (both-sides involution, rule #21).
// Measured structural optimum: counted-vmcnt pipelines (R5), 4 blocks/CU (R6),
// reg-B (R9/R13), grid-barrier fusion (R10), VGPR caps (R7) all regressed.
// Epilogue: 4-pass sequential combine in Red (aliases staging LDS), ks=0
// writes C in BF16 and atomically accumulates per-column sum/sumsq (f32).
__global__ __launch_bounds__(256, 2) void gemm_fused(const short* __restrict__ A,
                                                     const short* __restrict__ Bw,
                                                     short* __restrict__ C,
                                                     float* __restrict__ sums,
                                                     int K) {
  __shared__ __align__(16) char smem[49152];  // 2 x (As 16KB + Bs 8KB)
  int t = threadIdx.x;
  int ks = t >> 6, l = t & 63;
  int l31 = l & 31, hi = l >> 5;
  int bm = blockIdx.x, bn = blockIdx.y;
  const short* Ab = A + (long)(bm * 128) * CIN;
  const short* Bb = Bw + (long)(bn * 64) * K;

  f32x16 acc[4][2];
#pragma unroll
  for (int m = 0; m < 4; ++m)
#pragma unroll
    for (int n = 0; n < 2; ++n)
#pragma unroll
      for (int r = 0; r < 16; ++r) acc[m][n][r] = 0.f;

  // staging: 24 x 1KB chunks (A: 16, B: 8); wave ks stages A chunks 4ks..4ks+3
  // and B chunks 2ks..2ks+1. dest row = chunk*8 + (l>>3); source col
  // pre-swizzled so read-side byte^((row&7)<<4) is the matching involution.
  int l8 = l >> 3;
  int scol = ((l & 7) ^ l8) << 3;  // element offset of this lane's 16B chunk

#define STAGE(buf, k0)                                                                       \
  {                                                                                          \
    char* base = smem + (buf) * 24576;                                                       \
    int c0 = ks * 4, c1 = ks * 2;                                                            \
    gl_lds16(Ab + (long)((c0    ) * 8 + l8) * CIN + (k0) + scol, base + (c0    ) * 1024);    \
    gl_lds16(Ab + (long)((c0 + 1) * 8 + l8) * CIN + (k0) + scol, base + (c0 + 1) * 1024);    \
    gl_lds16(Ab + (long)((c0 + 2) * 8 + l8) * CIN + (k0) + scol, base + (c0 + 2) * 1024);    \
    gl_lds16(Ab + (long)((c0 + 3) * 8 + l8) * CIN + (k0) + scol, base + (c0 + 3) * 1024);    \
    gl_lds16(Bb + (long)((c1    ) * 8 + l8) * K + (k0) + scol, base + 16384 + (c1    ) * 1024); \
    gl_lds16(Bb + (long)((c1 + 1) * 8 + l8) * K + (k0) + scol, base + 16384 + (c1 + 1) * 1024); \
  }

  STAGE(0, 0);
  __syncthreads();

  // fragment read offsets: wave ks reads k-bytes [ks*32, ks*32+32) of each
  // 128B row; lane's 16B at kb = ks*32 + hi*16, XOR'd with ((row&7)<<4).
  int kb = ks * 32 + hi * 16;
  int sw = (l & 7) << 4;  // row&7 == l&7 since frag rows are m*32 + l31

  int nt = K >> 6;
  int cur = 0;
  for (int tix = 0; tix < nt; ++tix) {
    if (tix + 1 < nt) STAGE(cur ^ 1, (tix + 1) << 6);
    const char* AsC = smem + cur * 24576;
    const char* BsC = AsC + 16384;
    short8 a[4], b[2];
#pragma unroll
    for (int m = 0; m < 4; ++m)
      a[m] = *(const short8*)(AsC + (m * 32 + l31) * 128 + (kb ^ sw));
#pragma unroll
    for (int n = 0; n < 2; ++n)
      b[n] = *(const short8*)(BsC + (n * 32 + l31) * 128 + (kb ^ sw));
#pragma unroll
    for (int m = 0; m < 4; ++m)
#pragma unroll
      for (int n = 0; n < 2; ++n)
        acc[m][n] = __builtin_amdgcn_mfma_f32_32x32x16_bf16(a[m], b[n], acc[m][n], 0, 0, 0);
    __syncthreads();  // staged buf^1 complete + all reads of cur done
    cur ^= 1;
  }

  // ---- combine 4 K-quarters (Red aliases staging LDS), write bf16 C, stats ----
  float* Red = (float*)smem;  // 128x64 f32 = 32KB
#define RIDX(m, n, r) (((m) * 32 + ((r) & 3) + 8 * ((r) >> 2) + 4 * hi) * 64 + (n) * 32 + l31)
  if (ks == 3) {
#pragma unroll
    for (int m = 0; m < 4; ++m)
#pragma unroll
      for (int n = 0; n < 2; ++n)
#pragma unroll
        for (int r = 0; r < 16; ++r) Red[RIDX(m, n, r)] = acc[m][n][r];
  }
  __syncthreads();
  if (ks == 2) {
#pragma unroll
    for (int m = 0; m < 4; ++m)
#pragma unroll
      for (int n = 0; n < 2; ++n)
#pragma unroll
        for (int r = 0; r < 16; ++r) Red[RIDX(m, n, r)] += acc[m][n][r];
  }
  __syncthreads();
  if (ks == 1) {
#pragma unroll
    for (int m = 0; m < 4; ++m)
#pragma unroll
      for (int n = 0; n < 2; ++n)
#pragma unroll
        for (int r = 0; r < 16; ++r) Red[RIDX(m, n, r)] += acc[m][n][r];
  }
  __syncthreads();
  if (ks == 0) {
    short* Cb = C + (long)(bm * 128) * WIDTH + bn * 64;
#pragma unroll
    for (int n = 0; n < 2; ++n) {
      float s = 0.f, q = 0.f;
#pragma unroll
      for (int m = 0; m < 4; ++m) {
#pragma unroll
        for (int r = 0; r < 16; ++r) {
          int cr = (r & 3) + 8 * (r >> 2) + 4 * hi;
          float v = acc[m][n][r] + Red[RIDX(m, n, r)];
          Cb[(long)(m * 32 + cr) * WIDTH + n * 32 + l31] = f2bf(v);
          s += v; q += v * v;
        }
      }
      s += __shfl_xor(s, 32);
      q += __shfl_xor(q, 32);
      if (l < 32) {
        int colg = bn * 64 + n * 32 + l;
        atomicAdd(&sums[colg], s);
        atomicAdd(&sums[WIDTH + colg], q);
      }
    }
  }
#undef RIDX
#undef STAGE
}

// ---------------- BN + LeakyReLU + noise + classifier partial + bf16 store ----
__global__ __launch_bounds__(256) void bnact(const short* __restrict__ h,
                                             const float* __restrict__ sums,
                                             const float* __restrict__ gamma,
                                             const float* __restrict__ beta,
                                             const float* __restrict__ noise,
                                             const float* __restrict__ wc,
                                             short* __restrict__ lastseg,
                                             float* __restrict__ logit) {
  int w = threadIdx.x >> 6, l = threadIdx.x & 63;
  int r = blockIdx.x * 4 + w;
  int c = l * 8;
  const float invB = 1.0f / 8192.0f;
  short8 hb = *(const short8*)&h[(long)r * WIDTH + c];
  f32x4 n0 = *(const f32x4*)&noise[(long)r * WIDTH + c];
  f32x4 n1 = *(const f32x4*)&noise[(long)r * WIDTH + c + 4];
  float acc = 0.f;
  short8 ob;
#pragma unroll
  for (int j = 0; j < 8; ++j) {
    int cc = c + j;
    float hv = bf2f(hb[j]);
    float nv = j < 4 ? n0[j] : n1[j - 4];
    float mean = sums[cc] * invB;
    float var = sums[WIDTH + cc] * invB - mean * mean;
    float v = (hv - mean) * rsqrtf(var + EPS);
    v = v * gamma[cc] + beta[cc];
    v = v >= 0.f ? v : SLOPE * v;
    v *= nv;
    acc += v * wc[cc];
    ob[j] = f2bf(v);
  }
  *(short8*)&lastseg[(long)r * CIN + c] = ob;
#pragma unroll
  for (int off = 32; off; off >>= 1) acc += __shfl_xor(acc, off);
  if (l == 0) logit[r] += acc;  // one wave per row: no race
}

// ---- last layer: BN + act + classifier partial + sigmoid straight to out ----
// Layer 6's concat segment is never read again, so no lastbf store; lane 0
// holds the completed logit (x + layers 0..5 from `logit`, layer 6 from acc).
__global__ __launch_bounds__(256) void bnact_last(const short* __restrict__ h,
                                                  const float* __restrict__ sums,
                                                  const float* __restrict__ gamma,
                                                  const float* __restrict__ beta,
                                                  const float* __restrict__ noise,
                                                  const float* __restrict__ wc,
                                                  const float* __restrict__ logit,
                                                  const float* __restrict__ bc,
                                                  float* __restrict__ out) {
  int w = threadIdx.x >> 6, l = threadIdx.x & 63;
  int r = blockIdx.x * 4 + w;
  int c = l * 8;
  const float invB = 1.0f / 8192.0f;
  short8 hb = *(const short8*)&h[(long)r * WIDTH + c];
  f32x4 n0 = *(const f32x4*)&noise[(long)r * WIDTH + c];
  f32x4 n1 = *(const f32x4*)&noise[(long)r * WIDTH + c + 4];
  float acc = 0.f;
#pragma unroll
  for (int j = 0; j < 8; ++j) {
    int cc = c + j;
    float hv = bf2f(hb[j]);
    float nv = j < 4 ? n0[j] : n1[j - 4];
    float mean = sums[cc] * invB;
    float var = sums[WIDTH + cc] * invB - mean * mean;
    float v = (hv - mean) * rsqrtf(var + EPS);
    v = v * gamma[cc] + beta[cc];
    v = v >= 0.f ? v : SLOPE * v;
    v *= nv;
    acc += v * wc[cc];
  }
#pragma unroll
  for (int off = 32; off; off >>= 1) acc += __shfl_xor(acc, off);
  if (l == 0) {
    float z = logit[r] + acc + bc[0];
    out[r] = 1.0f / (1.0f + expf(-z));
  }
}

extern "C" void kernel_launch(void* const* d_in, const int* in_sizes, int n_in,
                              void* d_out, int out_size, void* d_ws, size_t ws_size,
                              hipStream_t stream) {
  (void)in_sizes; (void)n_in; (void)out_size; (void)ws_size;
  const float* x     = (const float*)d_in[0];
  WP wp;
  for (int i = 0; i < 7; ++i) wp.p[i] = (const float*)d_in[1 + i];
  // d_in[8] = b (linear bias) — cancels exactly through training-mode BN; unused.
  const float* gamma = (const float*)d_in[9];
  const float* beta  = (const float*)d_in[10];
  const float* Wc    = (const float*)d_in[11];
  const float* bc    = (const float*)d_in[12];
  const float* noise = (const float*)d_in[13];

  char* ws = (char*)d_ws;
  short* lastbf = (short*)ws;                               // 8192*4096 bf16 = 64 MiB
  short* hpre   = (short*)(ws + 67108864);                  // 8192*512 bf16 = 8 MiB
  short* wbf    = (short*)(ws + 67108864 + 16777216);       // 7.34M bf16    = 14 MiB
  float* sums   = (float*)(ws + 67108864 + 16777216 + 14680064);   // 7*1024 f32
  float* logit  = (float*)(ws + 67108864 + 16777216 + 14680064 + 28672);  // 8192 f32

  prolog<<<5632, 256, 0, stream>>>(wp, wbf, x, Wc, lastbf, logit, sums);

  long woff = 0;
  for (int i = 0; i < DEPTH; ++i) {
    int K = 512 * (i + 1);
    gemm_fused<<<dim3(64, 8), 256, 0, stream>>>(lastbf, wbf + woff, hpre,
                                                sums + i * 1024, K);
    if (i < DEPTH - 1) {
      bnact<<<2048, 256, 0, stream>>>(hpre, sums + i * 1024,
                                      gamma + i * 512, beta + i * 512,
                                      noise + (long)i * B_ROWS * WIDTH,
                                      Wc + 512 + i * 512,
                                      lastbf + 512 + (long)i * 512, logit);
    } else {
      bnact_last<<<2048, 256, 0, stream>>>(hpre, sums + i * 1024,
                                           gamma + i * 512, beta + i * 512,
                                           noise + (long)i * B_ROWS * WIDTH,
                                           Wc + 512 + i * 512,
                                           logit, bc, (float*)d_out);
    }
    woff += (long)512 * K;
  }
}